// Round 1
// baseline (515.769 us; speedup 1.0000x reference)
//
#include <hip/hip_runtime.h>
#include <cmath>

#define SOS 0
#define EOS 1
#define Bb 128
#define Ss 1024
#define Tt 128
#define LOG2E 1.4426950408889634f
#define LN2f  0.6931471805599453f

// ---------------------------------------------------------------------------
// Forward (partition) kernel: one block per batch element.
// Linear-space recurrence with register-resident exp(transition) matrix.
//   f' = (f @ expT) * w_i,  alpha = log2(f) + c
// Thread tile: ks = tid>>5 (8 groups of 16 k), js = tid&31 (32 groups of 4 j)
// ---------------------------------------------------------------------------
__global__ __launch_bounds__(256) void crf_forward(
    const float* __restrict__ em, const float* __restrict__ trans,
    const float* __restrict__ mask, float* __restrict__ part_out)
{
  __shared__ __align__(16) float s_trans[Tt * Tt];   // 64 KB, prologue + final
  __shared__ __align__(16) float s_f[Tt];
  __shared__ __align__(16) float s_part[8][Tt];
  __shared__ __align__(16) float s_em[4][Tt];        // emission prefetch ring
  __shared__ __align__(16) float s_mask[Ss];
  __shared__ float s_red[4];

  const int tid = threadIdx.x;
  const int b = blockIdx.x;
  const size_t em_base = (size_t)b * Ss * Tt;

  // ---- prologue: stage mask row and transition matrix ----
  for (int i = tid; i < Ss; i += 256) s_mask[i] = mask[b * Ss + i];
  #pragma unroll
  for (int it = 0; it < (Tt * Tt) / (256 * 4); ++it) {
    int idx = (it * 256 + tid) * 4;
    *(float4*)&s_trans[idx] = *(const float4*)&trans[idx];
  }
  __syncthreads();

  // register-resident exp2(trans * log2e) tile
  const int ks = tid >> 5;
  const int js = tid & 31;
  const int k0 = ks * 16, j0 = js * 4;
  float Mreg[16][4];
  #pragma unroll
  for (int kk = 0; kk < 16; ++kk)
    #pragma unroll
    for (int jj = 0; jj < 4; ++jj)
      Mreg[kk][jj] = exp2f(s_trans[(k0 + kk) * Tt + (j0 + jj)] * LOG2E);

  // ---- init: alpha0 = trans[SOS,:] + em[:,0,:]  (log2 domain) ----
  float a2 = -3.0e38f;
  if (tid < Tt) a2 = (s_trans[SOS * Tt + tid] + em[em_base + tid]) * LOG2E;
  float wm = a2;
  #pragma unroll
  for (int o = 32; o > 0; o >>= 1) wm = fmaxf(wm, __shfl_xor(wm, o));
  if ((tid & 63) == 0) s_red[tid >> 6] = wm;
  __syncthreads();
  const float m0 = fmaxf(s_red[0], s_red[1]);
  if (tid < Tt) s_f[tid] = exp2f(a2 - m0);
  float c_scale = m0;   // running log2-scale, maintained by finalize threads

  // prime emission ring: rows 1..3 into slots 1..3
  if (tid >= 128 && tid < 160) {
    int lt = tid - 128;
    #pragma unroll
    for (int r = 1; r <= 3; ++r)
      *(float4*)&s_em[r & 3][lt * 4] =
          *(const float4*)&em[em_base + (size_t)r * Tt + lt * 4];
  }
  __syncthreads();

  // ---- main recurrence ----
  for (int i = 1; i < Ss; ++i) {
    // phase A: all 256 threads — matvec partials
    float fr[16];
    *(float4*)&fr[0]  = *(float4*)&s_f[k0];
    *(float4*)&fr[4]  = *(float4*)&s_f[k0 + 4];
    *(float4*)&fr[8]  = *(float4*)&s_f[k0 + 8];
    *(float4*)&fr[12] = *(float4*)&s_f[k0 + 12];
    float acc0 = 0.f, acc1 = 0.f, acc2 = 0.f, acc3 = 0.f;
    #pragma unroll
    for (int kk = 0; kk < 16; ++kk) {
      float f = fr[kk];
      acc0 += f * Mreg[kk][0];
      acc1 += f * Mreg[kk][1];
      acc2 += f * Mreg[kk][2];
      acc3 += f * Mreg[kk][3];
    }
    *(float4*)&s_part[ks][j0] = make_float4(acc0, acc1, acc2, acc3);
    __syncthreads();

    // phase B
    if (tid < Tt) {
      const int j = tid;
      float g = ((s_part[0][j] + s_part[1][j]) + (s_part[2][j] + s_part[3][j]))
              + ((s_part[4][j] + s_part[5][j]) + (s_part[6][j] + s_part[7][j]));
      float w = exp2f(s_em[i & 3][j] * LOG2E);
      float fn = g * w;
      float mi = s_mask[i];
      float fold = s_f[j];
      if (mi == 0.0f) fn = fold;          // masked step: alpha unchanged

      if ((i & 3) == 0) {                 // apply rescale (measured at i-1)
        float M = fmaxf(s_red[0], s_red[1]);
        int e;
        (void)frexpf(M, &e);              // M = m * 2^e, m in [0.5,1)
        float scl = __int_as_float((127 - e) << 23);  // 2^-e
        fn *= scl;
        c_scale += (float)e;
      }
      if ((i & 3) == 3) {                 // measure max for next apply
        float v = fn;
        #pragma unroll
        for (int o = 32; o > 0; o >>= 1) v = fmaxf(v, __shfl_xor(v, o));
        if ((tid & 63) == 0) s_red[tid >> 6] = v;
      }
      s_f[j] = fn;
    } else if (tid < 160) {
      // spare lanes: prefetch emission row i+3 into ring slot (i+3)&3
      int r = i + 3;
      if (r < Ss) {
        int lt = tid - 128;
        *(float4*)&s_em[r & 3][lt * 4] =
            *(const float4*)&em[em_base + (size_t)r * Tt + lt * 4];
      }
    }
    __syncthreads();
  }

  // ---- partition = ln( sum_j f[j] * exp(trans[j,EOS]) ) + c*ln2 ----
  float v = 0.f;
  if (tid < Tt) {
    float tE2 = s_trans[tid * Tt + EOS] * LOG2E;
    v = s_f[tid] * exp2f(tE2);
  }
  #pragma unroll
  for (int o = 32; o > 0; o >>= 1) v += __shfl_xor(v, o);
  if ((tid & 63) == 0) s_red[tid >> 6] = v;
  __syncthreads();
  if (tid == 0) {
    float s = s_red[0] + s_red[1];
    part_out[b] = (log2f(s) + c_scale) * LN2f;
  }
}

// ---------------------------------------------------------------------------
// Score (numerator) kernel: one block per batch element, gather + reduce.
// ---------------------------------------------------------------------------
__global__ __launch_bounds__(256) void crf_score(
    const float* __restrict__ em, const float* __restrict__ trans,
    const float* __restrict__ mask, const int* __restrict__ tags,
    float* __restrict__ sc)
{
  __shared__ float s_red[4];
  __shared__ float s_red2[4];
  const int tid = threadIdx.x;
  const int b = blockIdx.x;
  const size_t em_base = (size_t)b * Ss * Tt;
  const int* tg = tags + b * Ss;
  const float* mk = mask + b * Ss;

  float part = 0.f, msum = 0.f;
  for (int i = tid; i < Ss; i += 256) {
    float m = mk[i];
    msum += m;
    if (i >= 1) {
      int tc = tg[i], tp = tg[i - 1];
      part += m * (em[em_base + (size_t)i * Tt + tc] + trans[tp * Tt + tc]);
    }
  }
  #pragma unroll
  for (int o = 32; o > 0; o >>= 1) {
    part += __shfl_xor(part, o);
    msum += __shfl_xor(msum, o);
  }
  if ((tid & 63) == 0) { s_red[tid >> 6] = part; s_red2[tid >> 6] = msum; }
  __syncthreads();
  if (tid == 0) {
    float p  = s_red[0] + s_red[1] + s_red[2] + s_red[3];
    float ms = s_red2[0] + s_red2[1] + s_red2[2] + s_red2[3];
    int last = (int)(ms + 0.5f) - 1;
    int t0 = tg[0];
    float s = trans[SOS * Tt + t0] + em[em_base + t0] + p
            + trans[tg[last] * Tt + EOS];
    sc[b] = s;
  }
}

// ---------------------------------------------------------------------------
// Combine: out = sum_b (partition[b] - score[b])
// ---------------------------------------------------------------------------
__global__ __launch_bounds__(128) void crf_combine(
    const float* __restrict__ part, const float* __restrict__ sc,
    float* __restrict__ out)
{
  __shared__ float s_red[2];
  const int tid = threadIdx.x;
  float v = part[tid] - sc[tid];
  #pragma unroll
  for (int o = 32; o > 0; o >>= 1) v += __shfl_xor(v, o);
  if ((tid & 63) == 0) s_red[tid >> 6] = v;
  __syncthreads();
  if (tid == 0) out[0] = s_red[0] + s_red[1];
}

extern "C" void kernel_launch(void* const* d_in, const int* in_sizes, int n_in,
                              void* d_out, int out_size, void* d_ws, size_t ws_size,
                              hipStream_t stream)
{
  const float* em    = (const float*)d_in[0];
  const float* trans = (const float*)d_in[1];
  const float* mask  = (const float*)d_in[2];
  const int*   tags  = (const int*)d_in[3];
  float* out = (float*)d_out;
  float* wsf = (float*)d_ws;
  float* part = wsf;          // [128]
  float* sc   = wsf + 128;    // [128]

  hipLaunchKernelGGL(crf_forward, dim3(Bb), dim3(256), 0, stream,
                     em, trans, mask, part);
  hipLaunchKernelGGL(crf_score, dim3(Bb), dim3(256), 0, stream,
                     em, trans, mask, tags, sc);
  hipLaunchKernelGGL(crf_combine, dim3(1), dim3(128), 0, stream,
                     part, sc, out);
}